// Round 1
// 568.938 us; speedup vs baseline: 1.0519x; 1.0519x over previous
//
#include <hip/hip_runtime.h>
#include <math.h>

namespace {

constexpr int N_ = 8, C_ = 256, S_ = 64, HW_ = 256;
constexpr int NS = N_ * S_;      // 512 columns (n,s)
constexpr int NHW = N_ * HW_;    // 2048 columns (n,hw)

// ---- workspace layout (float offsets) ----
constexpr size_t O_DESC  = 0;            // [512][256]
constexpr size_t O_DN    = 131072;
constexpr size_t O_MOT   = 393216;
constexpr size_t O_GATE  = 524288;
constexpr size_t O_MEM   = 786432;
constexpr size_t O_PHASE = 1048576;
constexpr size_t O_DELTA = 1441792;
constexpr size_t O_SCN   = 1572864;      // [512][512] scan out: fwd c<256, bwd c>=256
constexpr size_t O_SPT   = 2752512;      // [2048][256]
constexpr size_t O_SGATE = 3276800;      // [2048][256]
constexpr size_t O_FE    = 3801088;      // 264 used
constexpr size_t O_MFRE  = 3801600;
constexpr size_t O_MFIM  = 3802112;
constexpr size_t O_BW    = 3802656;      // [n][3]
constexpr size_t O_ATMF  = 3802688;
constexpr size_t O_ATMG  = 3868224;
constexpr size_t O_ATMO1 = 3999296;
constexpr size_t O_ATMO2 = 4195904;
constexpr size_t O_ATPP  = 4261440;
constexpr size_t O_ATBP1 = 4326976;
constexpr size_t O_ATBP2 = 4589120;
constexpr size_t O_ATFG  = 4654656;
constexpr size_t O_ATSG  = 4720192;
constexpr size_t O_WFRAG = 4785728;      // bf16 [168 kchunk][48 m16][64 lane][8]
constexpr size_t O_IM2   = 6850112;      // bf16 [168 kchunk][32 c16][64 lane][8]
constexpr size_t O_CONVC = 8226368;      // fp32 [4 kp][768][512]

typedef __attribute__((ext_vector_type(4))) float f32x4;
typedef __attribute__((ext_vector_type(8))) short s16x8;
typedef __attribute__((ext_vector_type(8))) unsigned short u16x8;

__device__ __forceinline__ float gelu_f(float v) {
  return 0.5f * v * (1.0f + erff(v * 0.70710678118654752f));
}
__device__ __forceinline__ float sigmoid_f(float v) {
  return 1.0f / (1.0f + expf(-v));
}
__device__ __forceinline__ unsigned short f2bf(float f) {
  unsigned int u = __float_as_uint(f);
  u += 0x7fffu + ((u >> 16) & 1u);
  return (unsigned short)(u >> 16);
}

// block (256 threads) sum with broadcast; scratch = 4 floats in LDS
__device__ __forceinline__ float block_sum256(float v, float* scratch) {
  #pragma unroll
  for (int off = 32; off; off >>= 1) v += __shfl_down(v, off, 64);
  int w = threadIdx.x >> 6;
  __syncthreads();
  if ((threadIdx.x & 63) == 0) scratch[w] = v;
  __syncthreads();
  return scratch[0] + scratch[1] + scratch[2] + scratch[3];
}

// peak params per n (26-element serial scan, uniform loads — bit-identical in all callers)
__device__ __forceinline__ void compute_pk(
    int n, const float* __restrict__ fe, const float* __restrict__ mfre,
    const float* __restrict__ mfim,
    float& conf, float& pnorm, float& dph, float& ang) {
  const float* f = fe + n * 33;
  float best = f[7]; int bidx = 0; float hs = 0.f;
  #pragma unroll
  for (int i = 0; i < 26; ++i) {
    float v = f[7 + i];
    hs += v;
    if (v > best) { best = v; bidx = i; }
  }
  int pi = bidx + 7;
  conf = best / fmaxf(hs, 1e-6f);
  pnorm = (float)pi * (1.f / 32.f);
  dph = atan2f(mfim[n * 33 + pi], mfre[n * 33 + pi]);
  ang = (6.283185307179586f / 64.f) * (float)pi;
}

// ---------------- weight prep: 1x1 transpose + conv A-fragment pack, one launch ----------------
__global__ __launch_bounds__(256) void weights_kernel(
    const float* __restrict__ wmf, const float* __restrict__ wmg,
    const float* __restrict__ wmo1, const float* __restrict__ wmo2,
    const float* __restrict__ wpp, const float* __restrict__ wbp1,
    const float* __restrict__ wbp2, const float* __restrict__ wfg,
    const float* __restrict__ wsg, float* __restrict__ ws,
    const float* __restrict__ w3, const float* __restrict__ w5,
    const float* __restrict__ w7, unsigned short* __restrict__ wf) {
  int bid = blockIdx.x;
  if (bid < 960) {
    __shared__ float tile[32][33];
    int xt = bid % 120, yt = bid / 120;
    const float* src; float* dst; int K;
    if      (xt < 8)   { src = wmf;  dst = ws + O_ATMF;  K = 256;  }
    else if (xt < 24)  { src = wmg;  dst = ws + O_ATMG;  K = 512;  xt -= 8;  }
    else if (xt < 48)  { src = wmo1; dst = ws + O_ATMO1; K = 768;  xt -= 24; }
    else if (xt < 56)  { src = wmo2; dst = ws + O_ATMO2; K = 256;  xt -= 48; }
    else if (xt < 64)  { src = wpp;  dst = ws + O_ATPP;  K = 256;  xt -= 56; }
    else if (xt < 96)  { src = wbp1; dst = ws + O_ATBP1; K = 1024; xt -= 64; }
    else if (xt < 104) { src = wbp2; dst = ws + O_ATBP2; K = 256;  xt -= 96; }
    else if (xt < 112) { src = wfg;  dst = ws + O_ATFG;  K = 256;  xt -= 104;}
    else               { src = wsg;  dst = ws + O_ATSG;  K = 256;  xt -= 112;}
    int tx = threadIdx.x & 31, ty = threadIdx.x >> 5;
    int c = xt * 32 + tx;
    #pragma unroll
    for (int i = 0; i < 4; ++i) {
      int r = yt * 32 + ty + i * 8;
      tile[ty + i * 8][tx] = src[(size_t)r * K + c];
    }
    __syncthreads();
    #pragma unroll
    for (int i = 0; i < 4; ++i) {
      int cc = xt * 32 + ty + i * 8;
      dst[(size_t)cc * 256 + yt * 32 + tx] = tile[tx][ty + i * 8];
    }
  } else {
    int g = (bid - 960) * 256 + threadIdx.x;       // one lane-slot
    int lane = g & 63;
    int m16 = (g >> 6) % 48;
    int kchunk = (g >> 6) / 48;
    int o = m16 * 16 + (lane & 15);
    int conv = o >> 8, oc = o & 255;
    int q = lane >> 4;
    u16x8 outv;
    #pragma unroll
    for (int j = 0; j < 8; ++j) {
      int k = kchunk * 32 + q * 8 + j;
      int ic = k / 7;
      int tau = k - ic * 7 - 3;
      float v = 0.f;
      if (conv == 0) {
        if (tau >= -1 && tau <= 1) v = w3[((size_t)oc * 768 + ic) * 3 + (tau + 1)];
      } else if (conv == 1) {
        if (tau >= -2 && tau <= 2) v = w5[((size_t)oc * 768 + ic) * 5 + (tau + 2)];
      } else {
        v = w7[((size_t)oc * 768 + ic) * 7 + (tau + 3)];
      }
      outv[j] = f2bf(v);
    }
    *((u16x8*)wf + g) = outv;
  }
}

// ---------------- pass 1: x reductions ----------------
__global__ __launch_bounds__(256) void reduce_x_kernel(
    const float* __restrict__ x, float* __restrict__ desc_t, float* __restrict__ sp_t) {
  int nc = blockIdx.x; int n = nc >> 8; int c = nc & 255;
  int t = threadIdx.x; int w = t >> 6; int l = t & 63;
  const float4* x4 = (const float4*)x + (size_t)nc * 4096;
  float4 sa = {0.f, 0.f, 0.f, 0.f};
  for (int i = 0; i < 16; ++i) {
    int s = w * 16 + i;
    float4 v = x4[(size_t)s * 64 + l];
    sa.x += v.x; sa.y += v.y; sa.z += v.z; sa.w += v.w;
    float ds = v.x + v.y + v.z + v.w;
    #pragma unroll
    for (int off = 32; off; off >>= 1) ds += __shfl_down(ds, off, 64);
    if (l == 0) desc_t[((size_t)n * 64 + s) * 256 + c] = ds * (1.f / 256.f);
  }
  __shared__ float4 lsp[4][64];
  lsp[w][l] = sa;
  __syncthreads();
  if (t < 64) {
    float4 a = lsp[0][t], b = lsp[1][t], c2 = lsp[2][t], d = lsp[3][t];
    float4 tot;
    tot.x = a.x + b.x + c2.x + d.x; tot.y = a.y + b.y + c2.y + d.y;
    tot.z = a.z + b.z + c2.z + d.z; tot.w = a.w + b.w + c2.w + d.w;
    size_t base = ((size_t)n * 256 + t * 4) * 256 + c;
    sp_t[base]       = tot.x * (1.f / 64.f);
    sp_t[base + 256] = tot.y * (1.f / 64.f);
    sp_t[base + 512] = tot.z * (1.f / 64.f);
    sp_t[base + 768] = tot.w * (1.f / 64.f);
  }
}

// ---------------- LayerNorm over C per (n,s) ----------------
__global__ __launch_bounds__(256) void ln_kernel(
    const float* __restrict__ desc_t, const float* __restrict__ g,
    const float* __restrict__ b, float* __restrict__ dn_t) {
  __shared__ float sc[4];
  int col = blockIdx.x; int t = threadIdx.x;
  float v = desc_t[(size_t)col * 256 + t];
  float s1 = block_sum256(v, sc);
  float s2 = block_sum256(v * v, sc);
  float mu = s1 * (1.f / 256.f);
  float var = s2 * (1.f / 256.f) - mu * mu;
  float r = rsqrtf(var + 1e-5f);
  dn_t[(size_t)col * 256 + t] = (v - mu) * r * g[t] + b[t];
}

// ---------------- fused: diffs + mg-gemm -> gate (block per col) ----------------
__global__ __launch_bounds__(256) void gate_kernel(
    const float* __restrict__ dn_t, const float* __restrict__ At_mg,
    const float* __restrict__ mg_b, float* __restrict__ gate_t) {
  __shared__ float gin[512];
  int col = blockIdx.x; int t = threadIdx.x; int s = col & 63;
  float d = dn_t[(size_t)col * 256 + t];
  float d1 = (s >= 1) ? d - dn_t[(size_t)(col - 1) * 256 + t] : 0.f;
  gin[t] = d;
  gin[256 + t] = fabsf(d1);
  __syncthreads();
  float a0 = 0.f, a1 = 0.f, a2 = 0.f, a3 = 0.f;
  #pragma unroll 4
  for (int k = 0; k < 512; k += 4) {
    a0 += At_mg[(size_t)(k + 0) * 256 + t] * gin[k + 0];
    a1 += At_mg[(size_t)(k + 1) * 256 + t] * gin[k + 1];
    a2 += At_mg[(size_t)(k + 2) * 256 + t] * gin[k + 2];
    a3 += At_mg[(size_t)(k + 3) * 256 + t] * gin[k + 3];
  }
  gate_t[(size_t)col * 256 + t] = sigmoid_f(((a0 + a1) + (a2 + a3)) + mg_b[t]);
}

// ---------------- fused: im2col B-fragments + rFFT, one launch ----------------
__global__ __launch_bounds__(256) void dnaux_kernel(
    const float* __restrict__ dn_t, unsigned short* __restrict__ imf,
    float* __restrict__ fe, float* __restrict__ mfre, float* __restrict__ mfim) {
  int bid = blockIdx.x;
  int t = threadIdx.x;
  if (bid < 1344) {
    int g = bid * 256 + t;
    int lane = g & 63;
    int c16 = (g >> 6) % 32;
    int kchunk = (g >> 6) / 32;
    int col = c16 * 16 + (lane & 15);
    int n = col >> 6, s = col & 63;
    int q = lane >> 4;
    const float* base = dn_t + (size_t)n * 16384;
    u16x8 outv;
    #pragma unroll
    for (int j = 0; j < 8; ++j) {
      int k = kchunk * 32 + q * 8 + j;
      int ic = k / 7;
      int tau = k - ic * 7 - 3;
      int stream = ic >> 8, c = ic & 255;
      int sp = s + tau;
      float v = 0.f;
      if (sp >= 0 && sp < 64) {
        float d = base[(size_t)sp * 256 + c];
        if (stream == 0) v = d;
        else if (stream == 1) v = (sp >= 1) ? d - base[(size_t)(sp - 1) * 256 + c] : 0.f;
        else v = (sp >= 2) ? d - base[(size_t)(sp - 2) * 256 + c] : 0.f;
      }
      outv[j] = f2bf(v);
    }
    *((u16x8*)imf + g) = outv;
  } else {
    int b = bid - 1344; int n = b / 33; int f = b % 33;
    __shared__ float cs[64], sn[64];
    __shared__ float sc[4];
    if (t < 64) {
      int ft = (f * t) & 63;
      float ang = -6.283185307179586f * (float)ft * (1.f / 64.f);
      cs[t] = cosf(ang); sn[t] = sinf(ang);
    }
    __syncthreads();
    float re = 0.f, im = 0.f;
    const float* base = dn_t + (size_t)n * 16384 + t;
    for (int s = 0; s < 64; ++s) {
      float v = base[(size_t)s * 256];
      re += v * cs[s]; im += v * sn[s];
    }
    re *= 0.125f; im *= 0.125f;   // ortho 1/sqrt(64)
    float mag = sqrtf(re * re + im * im);
    float sm = block_sum256(mag, sc);
    float sr = block_sum256(re, sc);
    float si = block_sum256(im, sc);
    if (t == 0) {
      fe[b]   = sm * (1.f / 256.f);
      mfre[b] = sr * (1.f / 256.f);
      mfim[b] = si * (1.f / 256.f);
    }
  }
}

// ---------------- conv as MFMA GEMM ----------------
__global__ __launch_bounds__(256) void conv_mfma_kernel(
    const unsigned short* __restrict__ wf, const unsigned short* __restrict__ imf,
    float* __restrict__ partial) {
  int mt = blockIdx.x, nt = blockIdx.y, kp = blockIdx.z;
  int lane = threadIdx.x & 63;
  int w = threadIdx.x >> 6;
  int m16 = mt * 4 + w;
  const s16x8* wfp = (const s16x8*)wf;
  const s16x8* imp = (const s16x8*)imf;
  f32x4 acc0 = {0.f,0.f,0.f,0.f}, acc1 = {0.f,0.f,0.f,0.f};
  f32x4 acc2 = {0.f,0.f,0.f,0.f}, acc3 = {0.f,0.f,0.f,0.f};
  #pragma unroll 2
  for (int cc = 0; cc < 42; ++cc) {
    int kc = kp * 42 + cc;
    s16x8 a = wfp[(size_t)(kc * 48 + m16) * 64 + lane];
    s16x8 b0 = imp[(size_t)(kc * 32 + nt * 4 + 0) * 64 + lane];
    s16x8 b1 = imp[(size_t)(kc * 32 + nt * 4 + 1) * 64 + lane];
    s16x8 b2 = imp[(size_t)(kc * 32 + nt * 4 + 2) * 64 + lane];
    s16x8 b3 = imp[(size_t)(kc * 32 + nt * 4 + 3) * 64 + lane];
    acc0 = __builtin_amdgcn_mfma_f32_16x16x32_bf16(a, b0, acc0, 0, 0, 0);
    acc1 = __builtin_amdgcn_mfma_f32_16x16x32_bf16(a, b1, acc1, 0, 0, 0);
    acc2 = __builtin_amdgcn_mfma_f32_16x16x32_bf16(a, b2, acc2, 0, 0, 0);
    acc3 = __builtin_amdgcn_mfma_f32_16x16x32_bf16(a, b3, acc3, 0, 0, 0);
  }
  int q = lane >> 4, ln = lane & 15;
  int o0 = m16 * 16 + q * 4;
  float* pb = partial + (size_t)kp * 393216;
  #pragma unroll
  for (int r = 0; r < 4; ++r) {
    size_t row = (size_t)(o0 + r) * 512;
    pb[row + (nt * 4 + 0) * 16 + ln] = acc0[r];
    pb[row + (nt * 4 + 1) * 16 + ln] = acc1[r];
    pb[row + (nt * 4 + 2) * 16 + ln] = acc2[r];
    pb[row + (nt * 4 + 3) * 16 + ln] = acc3[r];
  }
}

// ---------------- fused: combine(kp-sum + bn/gelu/avg) + mf-gemm -> motion (block per col) ----------------
__global__ __launch_bounds__(256) void motion_kernel(
    const float* __restrict__ P,
    const float* __restrict__ s3, const float* __restrict__ b3,
    const float* __restrict__ s5, const float* __restrict__ b5,
    const float* __restrict__ s7, const float* __restrict__ b7,
    const float* __restrict__ At_mf, const float* __restrict__ mf_s,
    const float* __restrict__ mf_b, float* __restrict__ motion_t) {
  __shared__ float ms[256];
  int col = blockIdx.x; int t = threadIdx.x;
  float v3 = 0.f, v5 = 0.f, v7 = 0.f;
  #pragma unroll
  for (int kp = 0; kp < 4; ++kp) {
    size_t base = (size_t)kp * 393216 + col;
    v3 += P[base + (size_t)t * 512];
    v5 += P[base + (size_t)(t + 256) * 512];
    v7 += P[base + (size_t)(t + 512) * 512];
  }
  float tot = gelu_f(v3 * s3[t] + b3[t]) + gelu_f(v5 * s5[t] + b5[t]) + gelu_f(v7 * s7[t] + b7[t]);
  ms[t] = tot * (1.f / 3.f);
  __syncthreads();
  float a0 = 0.f, a1 = 0.f, a2 = 0.f, a3 = 0.f;
  #pragma unroll 4
  for (int k = 0; k < 256; k += 4) {
    a0 += At_mf[(size_t)(k + 0) * 256 + t] * ms[k + 0];
    a1 += At_mf[(size_t)(k + 1) * 256 + t] * ms[k + 1];
    a2 += At_mf[(size_t)(k + 2) * 256 + t] * ms[k + 2];
    a3 += At_mf[(size_t)(k + 3) * 256 + t] * ms[k + 3];
  }
  motion_t[(size_t)col * 256 + t] = gelu_f(((a0 + a1) + (a2 + a3)) * mf_s[t] + mf_b[t]);
}

// ---------------- gated fwd/bwd scan over S (LDS-staged) -> scn [col][512] ----------------
__global__ __launch_bounds__(256) void scan_kernel(
    const float* __restrict__ dn_t, const float* __restrict__ gate_t, float* __restrict__ scn) {
  int n = blockIdx.x, half = blockIdx.y;
  int t = threadIdx.x;
  __shared__ float ld[64 * 128];
  __shared__ float lg[64 * 128];
  const float* dsrc = dn_t + (size_t)n * 16384 + half * 128;
  const float* gsrc = gate_t + (size_t)n * 16384 + half * 128;
  for (int i = t; i < 8192; i += 256) {
    int s = i >> 7, j = i & 127;
    ld[i] = dsrc[(size_t)s * 256 + j];
    lg[i] = gsrc[(size_t)s * 256 + j];
  }
  __syncthreads();
  int cl = t & 127;
  int c = half * 128 + cl;
  size_t ob = (size_t)n * 64 * 512 + c;
  if (t < 128) {
    float st = ld[cl];
    scn[ob] = st;
    for (int s = 1; s < 64; ++s) {
      float g = lg[s * 128 + cl], d = ld[s * 128 + cl];
      st = g * st + (1.f - g) * d;
      scn[ob + (size_t)s * 512] = st;
    }
  } else {
    float st = ld[63 * 128 + cl];
    scn[ob + (size_t)63 * 512 + 256] = st;
    for (int s = 62; s >= 0; --s) {
      float g = lg[s * 128 + cl], d = ld[s * 128 + cl];
      st = g * st + (1.f - g) * d;
      scn[ob + (size_t)s * 512 + 256] = st;
    }
  }
}

// ---------------- fused: mo1 + mo2 -> memory (block per col) ----------------
__global__ __launch_bounds__(256) void memory_kernel(
    const float* __restrict__ dn_t, const float* __restrict__ scn,
    const float* __restrict__ At1, const float* __restrict__ sc1, const float* __restrict__ bi1,
    const float* __restrict__ At2, float* __restrict__ mem_t) {
  __shared__ float bv[768];
  __shared__ float h[256];
  int col = blockIdx.x; int t = threadIdx.x;
  bv[t]       = dn_t[(size_t)col * 256 + t];
  bv[256 + t] = scn[(size_t)col * 512 + t];
  bv[512 + t] = scn[(size_t)col * 512 + 256 + t];
  __syncthreads();
  float a0 = 0.f, a1 = 0.f, a2 = 0.f, a3 = 0.f;
  #pragma unroll 4
  for (int k = 0; k < 768; k += 4) {
    a0 += At1[(size_t)(k + 0) * 256 + t] * bv[k + 0];
    a1 += At1[(size_t)(k + 1) * 256 + t] * bv[k + 1];
    a2 += At1[(size_t)(k + 2) * 256 + t] * bv[k + 2];
    a3 += At1[(size_t)(k + 3) * 256 + t] * bv[k + 3];
  }
  h[t] = gelu_f(((a0 + a1) + (a2 + a3)) * sc1[t] + bi1[t]);
  __syncthreads();
  float c0 = 0.f, c1 = 0.f, c2 = 0.f, c3 = 0.f;
  #pragma unroll 4
  for (int k = 0; k < 256; k += 4) {
    c0 += At2[(size_t)(k + 0) * 256 + t] * h[k + 0];
    c1 += At2[(size_t)(k + 1) * 256 + t] * h[k + 1];
    c2 += At2[(size_t)(k + 2) * 256 + t] * h[k + 2];
    c3 += At2[(size_t)(k + 3) * 256 + t] * h[k + 3];
  }
  mem_t[(size_t)col * 256 + t] = (c0 + c1) + (c2 + c3);
}

// ---------------- fused: peak recompute + pgate MLP + pp-gemm -> phase (block per col) ----------------
__global__ __launch_bounds__(256) void phase_kernel(
    const float* __restrict__ dn_t, const float* __restrict__ fe,
    const float* __restrict__ mfre, const float* __restrict__ mfim,
    const float* __restrict__ pg_w1, const float* __restrict__ pg_s1, const float* __restrict__ pg_b1,
    const float* __restrict__ pg_w2, const float* __restrict__ pg_b2,
    const float* __restrict__ At_pp, const float* __restrict__ pp_s, const float* __restrict__ pp_b,
    float* __restrict__ phase_t) {
  __shared__ float hh[64];
  __shared__ float pin[256];
  int col = blockIdx.x; int n = col >> 6; int s = col & 63; int t = threadIdx.x;
  float conf, pnorm, dph, ang;
  compute_pk(n, fe, mfre, mfim, conf, pnorm, dph, ang);
  (void)pnorm;
  float arg = ang * (float)s + dph;
  float pc = cosf(arg), ps = sinf(arg);
  if (t < 64) {
    float v = pg_w1[t * 3 + 0] * pc + pg_w1[t * 3 + 1] * ps + pg_w1[t * 3 + 2] * conf;
    hh[t] = gelu_f(v * pg_s1[t] + pg_b1[t]);
  }
  __syncthreads();
  float acc = pg_b2[t];
  const float* wrow = pg_w2 + t * 64;
  #pragma unroll 8
  for (int j = 0; j < 64; ++j) acc += wrow[j] * hh[j];
  pin[t] = dn_t[(size_t)col * 256 + t] * sigmoid_f(acc);
  __syncthreads();
  float a0 = 0.f, a1 = 0.f, a2 = 0.f, a3 = 0.f;
  #pragma unroll 4
  for (int k = 0; k < 256; k += 4) {
    a0 += At_pp[(size_t)(k + 0) * 256 + t] * pin[k + 0];
    a1 += At_pp[(size_t)(k + 1) * 256 + t] * pin[k + 1];
    a2 += At_pp[(size_t)(k + 2) * 256 + t] * pin[k + 2];
    a3 += At_pp[(size_t)(k + 3) * 256 + t] * pin[k + 3];
  }
  phase_t[(size_t)col * 256 + t] = gelu_f(((a0 + a1) + (a2 + a3)) * pp_s[t] + pp_b[t]);
}

// ---------------- router (peak recomputed inline) ----------------
__global__ __launch_bounds__(256) void router_kernel(
    const float* __restrict__ dn_t, const float* __restrict__ motion_t,
    const float* __restrict__ memory_t,
    const float* __restrict__ fe, const float* __restrict__ mfre,
    const float* __restrict__ mfim,
    const float* __restrict__ rt_w1, const float* __restrict__ rt_b1,
    const float* __restrict__ rt_w2, const float* __restrict__ rt_b2,
    float* __restrict__ bw) {
  int n = blockIdx.x; int c = threadIdx.x;
  __shared__ float ri[261];
  __shared__ float h2[64];
  __shared__ float lg[3];
  __shared__ float sc[4];
  float sum = 0.f, sq = 0.f, ad1 = 0.f, amot = 0.f, amem = 0.f, prev = 0.f;
  for (int s = 0; s < 64; ++s) {
    size_t i = ((size_t)n * 64 + s) * 256 + c;
    float d = dn_t[i];
    sum += d; sq += d * d;
    if (s > 0) ad1 += fabsf(d - prev);
    prev = d;
    amot += fabsf(motion_t[i]);
    amem += fabsf(memory_t[i] - d);
  }
  float mean = sum * (1.f / 64.f);
  float var = sq * (1.f / 64.f) - mean * mean;
  float stdc = sqrtf(fmaxf(var, 0.f));
  ri[c] = mean;
  float rstd = block_sum256(stdc, sc);
  float rad1 = block_sum256(ad1, sc);
  float rmot = block_sum256(amot, sc);
  float rmem = block_sum256(amem, sc);
  if (c == 0) {
    float conf, pnorm, dph, ang;
    compute_pk(n, fe, mfre, mfim, conf, pnorm, dph, ang);
    (void)dph; (void)ang;
    ri[256] = rstd * (1.f / 256.f);
    ri[257] = rad1 * (1.f / 16384.f);
    ri[258] = conf;
    ri[259] = pnorm;
    ri[260] = (rmem + rmot) * (1.f / 16384.f);
  }
  __syncthreads();
  if (c < 64) {
    float acc = rt_b1[c];
    const float* wrow = rt_w1 + c * 261;
    for (int i = 0; i < 261; ++i) acc += wrow[i] * ri[i];
    h2[c] = gelu_f(acc);
  }
  __syncthreads();
  if (c < 3) {
    float acc = rt_b2[c];
    const float* wrow = rt_w2 + c * 64;
    #pragma unroll 8
    for (int j = 0; j < 64; ++j) acc += wrow[j] * h2[j];
    lg[c] = acc;
  }
  __syncthreads();
  if (c == 0) {
    float m = fmaxf(lg[0], fmaxf(lg[1], lg[2]));
    float e0 = expf(lg[0] - m), e1 = expf(lg[1] - m), e2 = expf(lg[2] - m);
    float inv = 1.f / (e0 + e1 + e2);
    bw[n * 3 + 0] = e0 * inv; bw[n * 3 + 1] = e1 * inv; bw[n * 3 + 2] = e2 * inv;
  }
}

// ---------------- fused: fg-gemm + bp_prep + bp1 + bp2 + res_scale -> delta (block per col) ----------------
__global__ __launch_bounds__(256) void delta_kernel(
    const float* __restrict__ dn_t, const float* __restrict__ motion_t,
    const float* __restrict__ phase_t, const float* __restrict__ mem_t,
    const float* __restrict__ bw,
    const float* __restrict__ At_fg, const float* __restrict__ fg_b,
    const float* __restrict__ At1, const float* __restrict__ sc1, const float* __restrict__ bi1,
    const float* __restrict__ At2, const float* __restrict__ rs,
    float* __restrict__ delta_t) {
  __shared__ float bv[1024];
  __shared__ float h[256];
  int col = blockIdx.x; int n = col >> 6; int t = threadIdx.x;
  size_t i = (size_t)col * 256 + t;
  float d = dn_t[i], m = motion_t[i], p = phase_t[i], me = mem_t[i];
  float w0 = bw[n * 3 + 0], w1 = bw[n * 3 + 1], w2 = bw[n * 3 + 2];
  bv[t]       = d;
  bv[256 + t] = w0 * m + w1 * p + w2 * me;
  bv[512 + t] = m - p;
  bv[768 + t] = me - d;
  __syncthreads();
  // fgate = sigmoid(fg . dn + fg_b)
  float f0 = 0.f, f1 = 0.f, f2 = 0.f, f3 = 0.f;
  #pragma unroll 4
  for (int k = 0; k < 256; k += 4) {
    f0 += At_fg[(size_t)(k + 0) * 256 + t] * bv[k + 0];
    f1 += At_fg[(size_t)(k + 1) * 256 + t] * bv[k + 1];
    f2 += At_fg[(size_t)(k + 2) * 256 + t] * bv[k + 2];
    f3 += At_fg[(size_t)(k + 3) * 256 + t] * bv[k + 3];
  }
  float fgv = sigmoid_f(((f0 + f1) + (f2 + f3)) + fg_b[t]);
  // bp1
  float a0 = 0.f, a1 = 0.f, a2 = 0.f, a3 = 0.f;
  #pragma unroll 4
  for (int k = 0; k < 1024; k += 4) {
    a0 += At1[(size_t)(k + 0) * 256 + t] * bv[k + 0];
    a1 += At1[(size_t)(k + 1) * 256 + t] * bv[k + 1];
    a2 += At1[(size_t)(k + 2) * 256 + t] * bv[k + 2];
    a3 += At1[(size_t)(k + 3) * 256 + t] * bv[k + 3];
  }
  h[t] = gelu_f(((a0 + a1) + (a2 + a3)) * sc1[t] + bi1[t]);
  __syncthreads();
  // bp2 + fgate + res_scale
  float c0 = 0.f, c1 = 0.f, c2 = 0.f, c3 = 0.f;
  #pragma unroll 4
  for (int k = 0; k < 256; k += 4) {
    c0 += At2[(size_t)(k + 0) * 256 + t] * h[k + 0];
    c1 += At2[(size_t)(k + 1) * 256 + t] * h[k + 1];
    c2 += At2[(size_t)(k + 2) * 256 + t] * h[k + 2];
    c3 += At2[(size_t)(k + 3) * 256 + t] * h[k + 3];
  }
  delta_t[i] = ((c0 + c1) + (c2 + c3)) * fgv * rs[t];
}

// ---------------- generic 1x1-conv GEMM (kept for sgate): 1 col/wave ----------------
// EPI: 4 = sigmoid(v*sc+bi)
template <int K, int EPI>
__global__ __launch_bounds__(256) void gemm_kernel(
    const float* __restrict__ At, const float* __restrict__ B, float* __restrict__ out,
    const float* __restrict__ sc, const float* __restrict__ bi,
    const float* __restrict__ fg, const float* __restrict__ rs) {
  int t = threadIdx.x;
  int o = blockIdx.x * 64 + (t & 63);
  int col = blockIdx.y * 4 + (t >> 6);
  const float* bp = B + (size_t)col * K;
  float4 a0 = {0.f,0.f,0.f,0.f};
  for (int kk = 0; kk < K; kk += 4) {
    float4 b0 = *(const float4*)(bp + kk);
    a0.x += At[(size_t)(kk + 0) * 256 + o] * b0.x;
    a0.y += At[(size_t)(kk + 1) * 256 + o] * b0.y;
    a0.z += At[(size_t)(kk + 2) * 256 + o] * b0.z;
    a0.w += At[(size_t)(kk + 3) * 256 + o] * b0.w;
  }
  float v0 = (a0.x + a0.y) + (a0.z + a0.w);
  if constexpr (EPI == 4) { v0 = sigmoid_f(v0 * sc[o] + bi[o]); }
  out[(size_t)col * 256 + o] = v0;
}

// ---------------- pass 2: out = x + delta * sgate ----------------
__global__ __launch_bounds__(256) void final_kernel(
    const float* __restrict__ x, const float* __restrict__ delta_t,
    const float* __restrict__ sgate_t, float* __restrict__ out) {
  int nc = blockIdx.x; int n = nc >> 8; int c = nc & 255;
  int t = threadIdx.x;
  __shared__ float dlt[64];
  __shared__ float4 sgs4[64];
  if (t < 64) dlt[t] = delta_t[((size_t)n * 64 + t) * 256 + c];
  ((float*)sgs4)[t] = sgate_t[((size_t)n * 256 + t) * 256 + c];
  __syncthreads();
  const float4* x4 = (const float4*)x + (size_t)nc * 4096;
  float4* o4 = (float4*)out + (size_t)nc * 4096;
  int w = t >> 6, l = t & 63;
  float4 sg = sgs4[l];
  for (int i = 0; i < 16; ++i) {
    int s = w * 16 + i;
    float d = dlt[s];
    float4 v = x4[(size_t)s * 64 + l];
    v.x += d * sg.x; v.y += d * sg.y; v.z += d * sg.z; v.w += d * sg.w;
    o4[(size_t)s * 64 + l] = v;
  }
}

} // namespace

extern "C" void kernel_launch(void* const* d_in, const int* in_sizes, int n_in,
                              void* d_out, int out_size, void* d_ws, size_t ws_size,
                              hipStream_t stream) {
  const float* x      = (const float*)d_in[0];
  const float* ln_g   = (const float*)d_in[1];
  const float* ln_b   = (const float*)d_in[2];
  const float* mb_w3  = (const float*)d_in[3];
  const float* mb_s3  = (const float*)d_in[4];
  const float* mb_b3  = (const float*)d_in[5];
  const float* mb_w5  = (const float*)d_in[6];
  const float* mb_s5  = (const float*)d_in[7];
  const float* mb_b5  = (const float*)d_in[8];
  const float* mb_w7  = (const float*)d_in[9];
  const float* mb_s7  = (const float*)d_in[10];
  const float* mb_b7  = (const float*)d_in[11];
  const float* mf_w   = (const float*)d_in[12];
  const float* mf_s   = (const float*)d_in[13];
  const float* mf_b   = (const float*)d_in[14];
  const float* pg_w1  = (const float*)d_in[15];
  const float* pg_s1  = (const float*)d_in[16];
  const float* pg_b1  = (const float*)d_in[17];
  const float* pg_w2  = (const float*)d_in[18];
  const float* pg_b2  = (const float*)d_in[19];
  const float* pp_w   = (const float*)d_in[20];
  const float* pp_s   = (const float*)d_in[21];
  const float* pp_b   = (const float*)d_in[22];
  const float* mg_w   = (const float*)d_in[23];
  const float* mg_b   = (const float*)d_in[24];
  const float* mo_w1  = (const float*)d_in[25];
  const float* mo_s1  = (const float*)d_in[26];
  const float* mo_b1  = (const float*)d_in[27];
  const float* mo_w2  = (const float*)d_in[28];
  const float* rt_w1  = (const float*)d_in[29];
  const float* rt_b1  = (const float*)d_in[30];
  const float* rt_w2  = (const float*)d_in[31];
  const float* rt_b2  = (const float*)d_in[32];
  const float* bp_w1  = (const float*)d_in[33];
  const float* bp_s1  = (const float*)d_in[34];
  const float* bp_b1  = (const float*)d_in[35];
  const float* bp_w2  = (const float*)d_in[36];
  const float* res_sc = (const float*)d_in[37];
  const float* fg_w   = (const float*)d_in[38];
  const float* fg_b   = (const float*)d_in[39];
  const float* sg_w   = (const float*)d_in[40];
  const float* sg_s   = (const float*)d_in[41];
  const float* sg_b   = (const float*)d_in[42];
  float* ws = (float*)d_ws;
  float* out = (float*)d_out;
  unsigned short* wfrag = (unsigned short*)(ws + O_WFRAG);
  unsigned short* im2   = (unsigned short*)(ws + O_IM2);

  weights_kernel<<<2976, 256, 0, stream>>>(mf_w, mg_w, mo_w1, mo_w2, pp_w, bp_w1,
      bp_w2, fg_w, sg_w, ws, mb_w3, mb_w5, mb_w7, wfrag);
  reduce_x_kernel<<<2048, 256, 0, stream>>>(x, ws + O_DESC, ws + O_SPT);
  ln_kernel<<<512, 256, 0, stream>>>(ws + O_DESC, ln_g, ln_b, ws + O_DN);
  gate_kernel<<<512, 256, 0, stream>>>(ws + O_DN, ws + O_ATMG, mg_b, ws + O_GATE);
  dnaux_kernel<<<1608, 256, 0, stream>>>(ws + O_DN, im2, ws + O_FE, ws + O_MFRE, ws + O_MFIM);
  conv_mfma_kernel<<<dim3(12, 8, 4), 256, 0, stream>>>(wfrag, im2, ws + O_CONVC);
  motion_kernel<<<512, 256, 0, stream>>>(ws + O_CONVC, mb_s3, mb_b3, mb_s5, mb_b5,
      mb_s7, mb_b7, ws + O_ATMF, mf_s, mf_b, ws + O_MOT);
  scan_kernel<<<dim3(8, 2), 256, 0, stream>>>(ws + O_DN, ws + O_GATE, ws + O_SCN);
  memory_kernel<<<512, 256, 0, stream>>>(ws + O_DN, ws + O_SCN, ws + O_ATMO1,
      mo_s1, mo_b1, ws + O_ATMO2, ws + O_MEM);
  phase_kernel<<<512, 256, 0, stream>>>(ws + O_DN, ws + O_FE, ws + O_MFRE, ws + O_MFIM,
      pg_w1, pg_s1, pg_b1, pg_w2, pg_b2, ws + O_ATPP, pp_s, pp_b, ws + O_PHASE);
  router_kernel<<<8, 256, 0, stream>>>(ws + O_DN, ws + O_MOT, ws + O_MEM,
      ws + O_FE, ws + O_MFRE, ws + O_MFIM, rt_w1, rt_b1, rt_w2, rt_b2, ws + O_BW);
  delta_kernel<<<512, 256, 0, stream>>>(ws + O_DN, ws + O_MOT, ws + O_PHASE, ws + O_MEM,
      ws + O_BW, ws + O_ATFG, fg_b, ws + O_ATBP1, bp_s1, bp_b1, ws + O_ATBP2, res_sc,
      ws + O_DELTA);
  gemm_kernel<256, 4><<<dim3(4, 512), 256, 0, stream>>>(ws + O_ATSG, ws + O_SPT,
      ws + O_SGATE, sg_s, sg_b, nullptr, nullptr);
  final_kernel<<<2048, 256, 0, stream>>>(x, ws + O_DELTA, ws + O_SGATE, out);
}